// Round 10
// baseline (275.295 us; speedup 1.0000x reference)
//
#include <hip/hip_runtime.h>
#include <climits>

// Voxel hash: 2^22 u64 slots (key<<32 | min_point_id), ~1.98M voxels, load 0.47.
#define HCAP (1 << 22)
typedef unsigned long long u64;
typedef float f32x4 __attribute__((ext_vector_type(4)));
typedef float f32x2 __attribute__((ext_vector_type(2)));
#define EMPTY64 0xFFFFFFFFFFFFFFFFULL

// k_out geometry: 256 threads/block; 252 compute threads = 14 pl-groups x 18 c4;
// 224 points staged per block (14 x 16 iterations).
#define PB 224
#define TB 256

__device__ __forceinline__ unsigned fmix32(unsigned h) {
    h ^= h >> 16; h *= 0x85ebca6bu;
    h ^= h >> 13; h *= 0xc2b2ae35u;
    h ^= h >> 16;
    return h;
}

// Gold quant (verified round 7): XLA rewrites /0.02 -> *(1/0.02f); f32(1/0.02f)
// == 50.0f exactly. One f32 RN multiply + floor.
__device__ __forceinline__ int quant(float c) {
    return (int)floorf(c * 50.0f);
}

// K0: init packed table to EMPTY (16B vector stores)
__global__ void k_init(u64* __restrict__ tab) {
    int i = blockIdx.x * blockDim.x + threadIdx.x;
    if (i < HCAP / 2) {
        ulonglong2 v; v.x = EMPTY64; v.y = EMPTY64;
        ((ulonglong2*)tab)[i] = v;
    }
}

// K1: CAS-first claim/min into the packed table. All table accesses are
// atomics (no plain reads). Ids in a slot strictly decrease -> no livelock.
__global__ void k_build(const float* __restrict__ coord,
                        u64* __restrict__ tab, int* __restrict__ slotp, int n) {
    int i = blockIdx.x * blockDim.x + threadIdx.x;
    if (i >= n) return;
    int g0 = quant(coord[i * 3 + 0]);
    int g1 = quant(coord[i * 3 + 1]);
    int g2 = quant(coord[i * 3 + 2]);
    unsigned key = ((unsigned)(g0 & 1023) << 20) | ((unsigned)(g1 & 1023) << 10)
                 | (unsigned)(g2 & 1023);
    u64 packed = ((u64)key << 32) | (unsigned)i;

    unsigned h = fmix32(key) & (HCAP - 1);
    for (;;) {
        u64 old = atomicCAS(&tab[h], EMPTY64, packed);
        if (old == EMPTY64) break;                    // claimed fresh slot
        if ((unsigned)(old >> 32) == key) {           // our voxel's slot
            u64 cur = old;
            while ((unsigned)cur > (unsigned)i) {     // current min id > ours
                u64 prev = atomicCAS(&tab[h], cur, packed);
                if (prev == cur) break;
                cur = prev;                           // key stable post-claim
            }
            break;
        }
        h = (h + 1) & (HCAP - 1);                     // foreign key: probe on
    }
    slotp[i] = (int)h;
}

// K2: weights in REGISTERS (fixed c4 = t%18 column, 9 float4 = 36 VGPR).
// Stage 224 points' 9 inputs in LDS (broadcast-read later), then 16 iters of
// {9 scalar LDS reads, 36 FMA, 1 contiguous nt float4 store} per thread.
// Replaces 162 ds_read_b128/point (5.2 GB LDS traffic) with 9 b32/output.
__global__ __launch_bounds__(TB) void k_out(
        const float* __restrict__ feat, const float* __restrict__ coord,
        const float* __restrict__ W, const float* __restrict__ Wc,
        const int* __restrict__ slotp, const u64* __restrict__ tab,
        float* __restrict__ out, int n) {
    __shared__ float pv[PB * 9];
    int t = threadIdx.x;
    int base = blockIdx.x * PB;

    // Per-thread weight column (threads 252..255 idle in compute).
    int c4 = (t < 252) ? (t % 18) : 0;
    f32x4 w[9];
    #pragma unroll
    for (int q = 0; q < 6; ++q) w[q] = *(const f32x4*)&W[q * 72 + c4 * 4];
    #pragma unroll
    for (int q = 0; q < 3; ++q) w[6 + q] = *(const f32x4*)&Wc[q * 72 + c4 * 4];

    // Stage phase: one point per thread (t < PB).
    if (t < PB) {
        int p = base + t;
        if (p < n) {
            int r = (int)(unsigned)(tab[slotp[p]] & 0xFFFFFFFFu);  // min id
            const f32x2* fr2 = (const f32x2*)(feat + (size_t)r * 6); // 8B-aligned
            const float* cr = coord + (size_t)r * 3;
            f32x2 a = fr2[0], b = fr2[1], c = fr2[2];
            pv[t * 9 + 0] = a.x; pv[t * 9 + 1] = a.y;
            pv[t * 9 + 2] = b.x; pv[t * 9 + 3] = b.y;
            pv[t * 9 + 4] = c.x; pv[t * 9 + 5] = c.y;
            pv[t * 9 + 6] = cr[0]; pv[t * 9 + 7] = cr[1]; pv[t * 9 + 8] = cr[2];
        }
    }
    __syncthreads();

    if (t < 252) {
        int g = t / 18;                    // pl-group 0..13
        f32x4* out4 = (f32x4*)out;
        #pragma unroll
        for (int j = 0; j < 16; ++j) {
            int pl = j * 14 + g;           // covers 0..223 exactly
            int p = base + pl;
            if (p < n) {
                const float* vals = &pv[pl * 9];
                float v0 = vals[0];
                f32x4 acc;
                acc.x = v0 * w[0].x; acc.y = v0 * w[0].y;
                acc.z = v0 * w[0].z; acc.w = v0 * w[0].w;
                #pragma unroll
                for (int q = 1; q < 9; ++q) {
                    float v = vals[q];
                    acc.x = fmaf(v, w[q].x, acc.x);
                    acc.y = fmaf(v, w[q].y, acc.y);
                    acc.z = fmaf(v, w[q].z, acc.z);
                    acc.w = fmaf(v, w[q].w, acc.w);
                }
                __builtin_nontemporal_store(acc, &out4[(size_t)p * 18 + c4]);
            }
        }
    }
}

extern "C" void kernel_launch(void* const* d_in, const int* in_sizes, int n_in,
                              void* d_out, int out_size, void* d_ws, size_t ws_size,
                              hipStream_t stream) {
    const float* coord = (const float*)d_in[0];
    const float* feat  = (const float*)d_in[1];
    const float* W     = (const float*)d_in[2];
    const float* Wc    = (const float*)d_in[3];
    float* out = (float*)d_out;
    int n = in_sizes[0] / 3;

    // ws_size = 2.3 GB; we use 40 MB.
    u64* tab   = (u64*)d_ws;
    int* slotp = (int*)(tab + HCAP);

    k_init<<<(HCAP / 2 + 255) / 256, 256, 0, stream>>>(tab);
    k_build<<<(n + 255) / 256, 256, 0, stream>>>(coord, tab, slotp, n);
    k_out<<<(n + PB - 1) / PB, TB, 0, stream>>>(feat, coord, W, Wc, slotp, tab, out, n);
}